// Round 10
// baseline (345.806 us; speedup 1.0000x reference)
//
#include <hip/hip_runtime.h>
#include <hip/hip_bf16.h>

// MHA forward.  B=1, S=2048, H=1024, NH=16, DK=64.
// Inputs fp32, output fp32.  Internal bf16 MFMA pipeline, fp32 accum.
// Quirk: masked scores -> 0 (not -inf) BEFORE softmax; |scores| <= ~2 so
// softmax needs no max subtraction (m=0) and KV-split partials add.
// R18 (gemm_qkv only; rest = R17):
//  - A reg-staging deepened to 2 iterations (arA/arB named slots, same
//    schedule as gemm_out): aload(it+2) at iter top, awrite(it+1) after
//    MFMA.  R17's 1-deep pipeline was measured latency-bound (42.9us,
//    MfmaUtil 11%, VALUBusy 14%, HBM 12% -- all idle): the 8 fp32 loads
//    had only the ~400cy MFMA section to hide under.  Now they get a
//    full barrier period (~1500cy).  +64 VGPR, still < 170 cap for 3/CU.

#define S_LEN 2048
#define HID   1024
#define NHEAD 16
#define DK    64

typedef unsigned short u16;
typedef __attribute__((ext_vector_type(8))) short bf16x8;
typedef __attribute__((ext_vector_type(4))) short bf16x4;
typedef __attribute__((ext_vector_type(4))) float f32x4;
typedef __attribute__((ext_vector_type(2))) unsigned u32x2;
typedef __attribute__((ext_vector_type(4))) unsigned u32x4;

__device__ __forceinline__ void load16_lds(const void* g, void* l) {
  __builtin_amdgcn_global_load_lds(
      (const __attribute__((address_space(1))) void*)g,
      (__attribute__((address_space(3))) void*)l, 16, 0, 0);
}

__device__ __forceinline__ short bfbits(float x) {
  __hip_bfloat16 h = __float2bfloat16(x);
  return *(short*)&h;
}
__device__ __forceinline__ bf16x8 cvt8(float4 a, float4 b) {
  bf16x8 r;
  r[0] = bfbits(a.x); r[1] = bfbits(a.y); r[2] = bfbits(a.z); r[3] = bfbits(a.w);
  r[4] = bfbits(b.x); r[5] = bfbits(b.y); r[6] = bfbits(b.z); r[7] = bfbits(b.w);
  return r;
}
__device__ __forceinline__ float bf2f(u16 u) {
  unsigned v = (unsigned)u << 16;
  return *(float*)&v;
}

// ---------------------------------------------------------------------------
// 0. cvt Wq,Wk,Wv,Wo fp32 -> bf16 (y<4)  AND  pack mask (y==4, row-major).
// ---------------------------------------------------------------------------
__global__ __launch_bounds__(256) void cvt_pack_kernel(
    const float* __restrict__ wq, const float* __restrict__ wk,
    const float* __restrict__ wv, const float* __restrict__ wo,
    const int* __restrict__ mask, u16* __restrict__ Wbf,
    unsigned int* __restrict__ bits) {
  const int y = blockIdx.y;
  if (y == 4) {                       // pack mask -> row-major bitfield
    if (blockIdx.x >= 512) return;
    int idx = blockIdx.x * 256 + threadIdx.x;   // 0 .. 2048*64-1
    const int4* p = (const int4*)(mask + (size_t)idx * 32);
    unsigned word = 0;
#pragma unroll
    for (int i = 0; i < 8; ++i) {
      int4 mv = p[i];
      word |= (unsigned)(mv.x != 0) << (i * 4 + 0);
      word |= (unsigned)(mv.y != 0) << (i * 4 + 1);
      word |= (unsigned)(mv.z != 0) << (i * 4 + 2);
      word |= (unsigned)(mv.w != 0) << (i * 4 + 3);
    }
    bits[idx] = word;
    return;
  }
  if (blockIdx.x >= 512) return;      // 1M elems / 8 / 256 = 512 blocks
  size_t i = ((size_t)blockIdx.x * 256 + threadIdx.x) * 8;
  const float* src = y == 0 ? wq : (y == 1 ? wk : (y == 2 ? wv : wo));
  u16* dst = Wbf + (size_t)y * (HID * HID);
  float4 a = *(const float4*)(src + i);
  float4 b = *(const float4*)(src + i + 4);
  *(bf16x8*)(dst + i) = cvt8(a, b);
}

// ---------------------------------------------------------------------------
// 2. QKV GEMM fused over N=3072: Y = X_z @ W^T + b, z = colgroup>>10.
//    BM=128, BN=64, BK=64, 256 thr / 4 waves, wave tile 64x32.
//    Grid 768 = 3/CU exactly (LDS 48KB, lb(256,3)).
//    A staged REG->LDS with fused fp32->bf16 cvt, TWO iterations deep
//    (arA/arB slots, gemm_out schedule); B staged via global_load_lds.
//    XCD mapping: 4m x 24n per XCD.  B-LDS slot permutation for
//    adjacent-col packed b32 stores.  z=0: *0.125*log2(e) -> Qb ;
//    z=1 -> Kb ; z=2 -> Vt transposed via LDS (coalesced), kv rows
//    permuted so position p holds kv = ((p&7)>>2)*16+(p>>3)*4+(p&3).
// ---------------------------------------------------------------------------
__global__ __launch_bounds__(256, 3) void gemm_qkv(
    const float* __restrict__ qx, const float* __restrict__ kx,
    const float* __restrict__ vx, const u16* __restrict__ Wbf,
    const float* __restrict__ bq, const float* __restrict__ bk,
    const float* __restrict__ bv, u16* __restrict__ Qb,
    u16* __restrict__ Kb, u16* __restrict__ Vt) {
  constexpr int Mm = 2048, Kk = 1024, NIT = 16;
  const int tid = threadIdx.x, lane = tid & 63, wave = tid >> 6;
  const int q4 = lane >> 4, c16 = lane & 15;
  const int bx = blockIdx.x;                    // 768 blocks
  const int xcd = bx & 7, s = bx >> 3;          // s in [0,96)
  const int mh = s / 24;                        // 0..3
  const int mBase = ((xcd >> 1) * 4 + mh) * 128;
  const int nG = (xcd & 1) * 24 + (s - mh * 24);  // 0..47
  const int nBase = nG * 64;
  const int z = nBase >> 10;
  const float* Araw = z == 0 ? qx : (z == 1 ? kx : vx);
  const float* bias = z == 0 ? bq : (z == 1 ? bk : bv);
  const float oscale = (z == 0) ? 0.125f * 1.44269504088896f : 1.0f;

  const int wr = wave >> 1, wc = wave & 1;      // wave tile 64x32

  __shared__ __align__(16) u16 As[2][2][128 * 32];
  __shared__ __align__(16) u16 Bs[2][2][64 * 32];

  f32x4 acc[4][2] = {};
  const int srow = lane >> 2;
  const int sx8 = ((lane & 3) ^ ((srow >> 1) & 3)) * 8;
  const int rx8 = (q4 ^ ((c16 >> 1) & 3)) * 8;

  // A reg-staging, 2-deep (arA even tiles, arB odd tiles): fp32 source at
  // the same swizzled elem offset; dest slot = linear lane*16B.
  float4 arA[4][2], arB[4][2];
  auto aloadTo = [&](float4 (*dst)[2], int it) {
#pragma unroll
    for (int j = 0; j < 4; ++j) {
      int u = wave * 4 + j, h = u >> 3, grp = u & 7;
      const float* p = Araw + (size_t)(mBase + grp * 16 + srow) * Kk +
                       it * 64 + h * 32 + sx8;
      dst[j][0] = *(const float4*)p;
      dst[j][1] = *(const float4*)(p + 4);
    }
  };
  auto awriteFrom = [&](const float4 (*src)[2], int buf) {
#pragma unroll
    for (int j = 0; j < 4; ++j) {
      int u = wave * 4 + j, h = u >> 3, grp = u & 7;
      *(bf16x8*)&As[buf][h][grp * 512 + lane * 8] = cvt8(src[j][0], src[j][1]);
    }
  };

  auto issueB = [&](int it, int buf) {
#pragma unroll
    for (int j = 0; j < 2; ++j) {      // B: 8 units; slot row -> permuted src
      int u = wave * 2 + j, h = u >> 2, grp = u & 3;
      int brow = grp * 16 + srow;                 // LDS slot row 0..63
      int b32 = brow & 31;
      int bsrc = (brow & 32) | ((b32 & 15) * 2 + (b32 >> 4));
      load16_lds(Wbf + (size_t)(nBase + bsrc) * Kk + it * 64 +
                     h * 32 + sx8,
                 &Bs[buf][h][grp * 512]);
    }
  };

  // prologue: tile0 -> LDS buf0; tile1 loaded into arB (written at it=0 end).
  aloadTo(arA, 0);
  issueB(0, 0);
  awriteFrom(arA, 0);
  aloadTo(arB, 1);
  __syncthreads();

  for (int it = 0; it < NIT; ++it) {
    const int buf = it & 1, nbuf = buf ^ 1;
    if (it + 1 < NIT) issueB(it + 1, nbuf);
    if (it + 2 < NIT) aloadTo((it & 1) ? arB : arA, it + 2);  // slot (it+2)&1
#pragma unroll
    for (int kk = 0; kk < 2; ++kk) {
      bf16x8 af[4], bfr[2];
#pragma unroll
      for (int t = 0; t < 4; ++t)
        af[t] = *(const bf16x8*)&As[buf][kk][(wr * 64 + t * 16 + c16) * 32 + rx8];
#pragma unroll
      for (int t = 0; t < 2; ++t)
        bfr[t] = *(const bf16x8*)&Bs[buf][kk][(wc * 32 + t * 16 + c16) * 32 + rx8];
#pragma unroll
      for (int mt = 0; mt < 4; ++mt)
#pragma unroll
        for (int nt = 0; nt < 2; ++nt)
          acc[mt][nt] = __builtin_amdgcn_mfma_f32_16x16x32_bf16(
              af[mt], bfr[nt], acc[mt][nt], 0, 0, 0);
    }
    if (it + 1 < NIT) awriteFrom((it & 1) ? arA : arB, nbuf);  // slot (it+1)&1
    __syncthreads();
  }

  // lane's two output cols are ADJACENT: colE, colE+1 (B slot permutation).
  const int colE = wc * 32 + c16 * 2;            // local col, even
  if (z == 2) {
    // ---- LDS transpose: LT[64 cols][132] (reuses As, 16.9KB) ----
    u16* LT = (u16*)&As[0][0][0];
#pragma unroll
    for (int nt = 0; nt < 2; ++nt) {
      int col = colE + nt;
      float bv2 = bias[((nBase & 1023) + col)];
#pragma unroll
      for (int mt = 0; mt < 4; ++mt) {
        int row0 = wr * 64 + mt * 16 + q4 * 4;   // low 2 bits zero
        int vv0 = row0 & 31;
        int rowp0 = (row0 & ~31) | (((vv0 & 15) >> 2) << 3) |
                    (((vv0 >> 4) & 1) << 2);
        bf16x4 t;
#pragma unroll
        for (int r = 0; r < 4; ++r) t[r] = bfbits(acc[mt][nt][r] + bv2);
        *(bf16x4*)&LT[col * 132 + rowp0] = t;
      }
    }
    __syncthreads();
    // readout: 4 reps x 256 thr; 16B coalesced stores along kv.
#pragma unroll
    for (int rep = 0; rep < 4; ++rep) {
      int u = rep * 256 + tid;
      int col = u >> 4, seg = u & 15;
      bf16x8 vvv = *(const bf16x8*)&LT[col * 132 + seg * 8];
      *(bf16x8*)(Vt + (size_t)((nBase & 1023) + col) * Mm + mBase + seg * 8) = vvv;
    }
  } else {
    u16* C = z == 0 ? Qb : Kb;
    int colg = (nBase & 1023) + colE;
    float2 b2 = *(const float2*)&bias[colg];
#pragma unroll
    for (int mt = 0; mt < 4; ++mt) {
#pragma unroll
      for (int r = 0; r < 4; ++r) {
        int row = mBase + wr * 64 + mt * 16 + q4 * 4 + r;
        float v0 = (acc[mt][0][r] + b2.x) * oscale;
        float v1 = (acc[mt][1][r] + b2.y) * oscale;
        unsigned pk;
        asm("v_cvt_pk_bf16_f32 %0, %1, %2" : "=v"(pk) : "v"(v0), "v"(v1));
        *(unsigned*)&C[(size_t)row * 1024 + colg] = pk;
      }
    }
  }
}

// ---------------------------------------------------------------------------
// 3. Attention.  8 waves x 32 q-rows = 256 rows/block, 512 thr, KV-split
//    z=4, NITA=8, XCD remap.  SWAPPED QK^T (mfma(K,Q)): lane holds
//    q=c16, kv=q4*4+r -> P packs in-register into the PV A-frag (no LDS
//    P, no lgkmcnt stall).  LDS = K/V dbuf only (33KB); 16 waves/CU.
// ---------------------------------------------------------------------------
__global__ __launch_bounds__(512, 4) void attn_kernel(
    const u16* __restrict__ Qb, const u16* __restrict__ Kb,
    const u16* __restrict__ Vt, const unsigned* __restrict__ mb,
    u16* __restrict__ partOA, u16* __restrict__ partO3,
    float* __restrict__ partL) {
  constexpr int NITA = 8;                       // 512 kv / 64
  const int lin = blockIdx.x + 8 * (blockIdx.y + 16 * blockIdx.z);
  const int work = ((lin & 7) << 6) | (lin >> 3);
  const int qt = work & 7, h = (work >> 3) & 15, zz = work >> 7;
  const int tid = threadIdx.x, lane = tid & 63, wave = tid >> 6;
  const int q4 = lane >> 4, c16 = lane & 15;

  __shared__ __align__(16) u16 Ks[2][2][64 * 32];
  __shared__ __align__(16) u16 Vs[2][2][64 * 32];

  const int q0 = qt * 256 + wave * 32;

  bf16x8 qf[2][2];
#pragma unroll
  for (int m = 0; m < 2; ++m)
#pragma unroll
    for (int kk = 0; kk < 2; ++kk)
      qf[m][kk] = *(const bf16x8*)(Qb + (size_t)(q0 + m * 16 + c16) * HID +
                                   h * DK + kk * 32 + q4 * 8);

  f32x4 o[2][4] = {};
  float l_lane[2] = {0.0f, 0.0f};

  const int srow = lane >> 2;
  const int sx8 = ((lane & 3) ^ ((srow >> 1) & 3)) * 8;
  const int rx8 = (q4 ^ ((c16 >> 1) & 3)) * 8;
  const int kvbase = zz * (S_LEN / 4);

  auto issueKV = [&](int it, int buf) {
    const int kv0 = kvbase + it * 64;
#pragma unroll
    for (int j = 0; j < 2; ++j) {
      int i = wave * 2 + j;          // 0..15
      if (i < 8) {
        int half = i >> 2, grp = i & 3;
        load16_lds(Kb + (size_t)(kv0 + grp * 16 + srow) * HID + h * DK +
                       half * 32 + sx8,
                   &Ks[buf][half][grp * 512]);
      } else {
        int ii = i - 8;
        int half = ii >> 2, grp = ii & 3;
        load16_lds(Vt + (size_t)(h * DK + grp * 16 + srow) * S_LEN + kv0 +
                       half * 32 + sx8,
                   &Vs[buf][half][grp * 512]);
      }
    }
  };

  issueKV(0, 0);
  __syncthreads();

  for (int it = 0; it < NITA; ++it) {
    const int buf = it & 1, nbuf = buf ^ 1;
    if (it + 1 < NITA) issueKV(it + 1, nbuf);

    // mask words: lane's q-row, 2 consecutive kv-words (this 64-kv stripe).
    u32x2 mw[2];
#pragma unroll
    for (int m = 0; m < 2; ++m)
      mw[m] = *(const u32x2*)(mb + (size_t)(q0 + m * 16 + c16) * 64 +
                              (kvbase >> 5) + it * 2);

#pragma unroll
    for (int kk = 0; kk < 2; ++kk) {        // kv-chunk of 32
      // ---- QK^T (swapped): sv[m][ntb] = S^T[kv-tile nt][q] ----
      f32x4 sv[2][2];
      __builtin_amdgcn_s_setprio(1);
#pragma unroll
      for (int ntb = 0; ntb < 2; ++ntb) {
        const int nt = kk * 2 + ntb;
        const int rsw = (nt * 16 + c16) * 32 + rx8;
        bf16x8 kf0 = *(const bf16x8*)&Ks[buf][0][rsw];
        bf16x8 kf1 = *(const bf16x8*)&Ks[buf][1][rsw];
#pragma unroll
        for (int m = 0; m < 2; ++m) {
          f32x4 a = {};
          a = __builtin_amdgcn_mfma_f32_16x16x32_bf16(kf0, qf[m][0], a, 0, 0, 0);
          a = __builtin_amdgcn_mfma_f32_16x16x32_bf16(kf1, qf[m][1], a, 0, 0, 0);
          sv[m][ntb] = a;
        }
      }
      __builtin_amdgcn_s_setprio(0);

      // ---- softmax + in-register pack into PV A-frags ----
      bf16x8 pa[2];
#pragma unroll
      for (int m = 0; m < 2; ++m) {
        const unsigned word = kk ? mw[m][1] : mw[m][0];
        float p[8];
#pragma unroll
        for (int ntb = 0; ntb < 2; ++ntb)
#pragma unroll
          for (int r = 0; r < 4; ++r) {
            const int bit = ntb * 16 + q4 * 4 + r;
            float s = ((word >> bit) & 1u) ? sv[m][ntb][r] : 0.0f;
            float e;
            asm("v_exp_f32 %0, %1" : "=v"(e) : "v"(s));  // log2e pre-folded
            l_lane[m] += e;
            p[ntb * 4 + r] = e;
          }
        u32x4 pk;
#pragma unroll
        for (int j = 0; j < 4; ++j)
          asm("v_cvt_pk_bf16_f32 %0, %1, %2"
              : "=v"(pk[j]) : "v"(p[2 * j]), "v"(p[2 * j + 1]));
        pa[m] = *(bf16x8*)&pk;
      }

      // ---- PV for this kv-chunk ----
      __builtin_amdgcn_s_setprio(1);
#pragma unroll
      for (int ntv = 0; ntv < 4; ++ntv) {
        const int rsw = (ntv * 16 + c16) * 32 + rx8;
        bf16x8 vb = *(const bf16x8*)&Vs[buf][kk][rsw];
        o[0][ntv] = __builtin_amdgcn_mfma_f32_16x16x32_bf16(pa[0], vb, o[0][ntv], 0, 0, 0);
        o[1][ntv] = __builtin_amdgcn_mfma_f32_16x16x32_bf16(pa[1], vb, o[1][ntv], 0, 0, 0);
      }
      __builtin_amdgcn_s_setprio(0);
    }
    __syncthreads();
  }

  u16* pO = (zz < 3) ? (partOA + (size_t)zz * (S_LEN * HID)) : partO3;
#pragma unroll
  for (int m = 0; m < 2; ++m) {
    float s = l_lane[m];
    s += __shfl_xor(s, 16);
    s += __shfl_xor(s, 32);
    int qrow = q0 + m * 16 + c16;
    if (q4 == 0)
      partL[((size_t)zz * NHEAD + h) * S_LEN + qrow] = s;
#pragma unroll
    for (int r = 0; r < 4; ++r) {
      int row = q0 + m * 16 + q4 * 4 + r;
#pragma unroll
      for (int nt = 0; nt < 4; ++nt)
        ((__hip_bfloat16*)pO)[(size_t)row * HID + h * DK + nt * 16 + c16] =
            __float2bfloat16(o[m][nt][r]);
    }
  }
}

// ---------------------------------------------------------------------------
// 5. Output GEMM with fused combine: out = ((O0+O1+O2+O3)/l) @ Wo^T + bo.
//    BM=32, BN=128, 512 blocks = 2/CU, XCD chunking.  A staging pipelined
//    2 iters ahead (avA/avB named slots -> static indexing, rule 20).
// ---------------------------------------------------------------------------
__global__ __launch_bounds__(256) void gemm_out(
    const u16* __restrict__ pOA, const u16* __restrict__ pO3,
    const float* __restrict__ partL, const u16* __restrict__ Wo,
    const float* __restrict__ bo, float* __restrict__ out) {
  constexpr int Nn = 1024, Kk = 1024, NIT = 16;
  constexpr size_t M2 = (size_t)S_LEN * HID;
  const int tid = threadIdx.x, lane = tid & 63, wave = tid >> 6;
  const int q4 = lane >> 4, c16 = lane & 15;
  const int bx = blockIdx.x;
  const int xcd = bx & 7, s = bx >> 3;          // s in [0,64)
  const int mBase = (xcd * 8 + (s & 7)) * 32;
  const int nBase = (s >> 3) * 128;
  const int wn = wave * 32;

  __shared__ __align__(16) u16 As[2][2][32 * 32];
  __shared__ __align__(16) u16 Bs[2][2][128 * 32];
  __shared__ float linv[32][16];

  f32x4 acc[2][2] = {};
  const int srow = lane >> 2;
  const int sx8 = ((lane & 3) ^ ((srow >> 1) & 3)) * 8;
  const int rx8 = (q4 ^ ((c16 >> 1) & 3)) * 8;

  const int arow = tid >> 3, acu = tid & 7;     // A unit: row 0..31, colu 0..7
  const int ahalf = acu >> 2;
  const int aoff = arow * 32 + ((acu & 3) ^ ((arow >> 1) & 3)) * 8;

  auto issueB = [&](int it, int buf) {
#pragma unroll
    for (int j = 0; j < 4; ++j) {       // B: 16 units
      int u = wave * 4 + j, h = u >> 3, grp = u & 7;
      load16_lds(Wo + (size_t)(nBase + grp * 16 + srow) * Kk + it * 64 +
                     h * 32 + sx8,
                 &Bs[buf][h][grp * 512]);
    }
  };

  bf16x8 avA[4], avB[4];
  auto aloadTo = [&](bf16x8* dst, int it) {
    const u16* p = pOA + (size_t)(mBase + arow) * Kk + it * 64 + acu * 8;
    dst[0] = *(const bf16x8*)p;
    dst[1] = *(const bf16x8*)(p + M2);
    dst[2] = *(const bf16x8*)(p + 2 * M2);
    dst[3] = *(const bf16x8*)(pO3 + (size_t)(mBase + arow) * Kk + it * 64 + acu * 8);
  };
  auto awriteFrom = [&](const bf16x8* src, int it, int buf) {
    float inv = linv[arow][it];        // BK=64=DK: one head per K-step
    bf16x8 r;
#pragma unroll
    for (int j = 0; j < 8; ++j) {
      float v = (bf2f((u16)src[0][j]) + bf2f((u16)src[1][j]) +
                 bf2f((u16)src[2][j]) + bf2f((u16)src[3][j])) * inv;
      r[j] = bfbits(v);
    }
    *(bf16x8*)&As[buf][ahalf][aoff] = r;
  };

  // prologue: 1/l table (32 rows x 16 heads), A slots 0,1, B tile 0.
#pragma unroll
  for (int e = 0; e < 2; ++e) {
    int idx = tid * 2 + e, row = idx >> 4, hh = idx & 15;
    float l = 0.0f;
#pragma unroll
    for (int z = 0; z < 4; ++z)
      l += partL[(size_t)(z * NHEAD + hh) * S_LEN + mBase + row];
    linv[row][hh] = 1.0f / l;
  }
  aloadTo(avA, 0);
  issueB(0, 0);
  __syncthreads();            // linv visible (B0 also drains)
  awriteFrom(avA, 0, 0);
  aloadTo(avB, 1);
  __syncthreads();            // As[0] + Bs[0] ready

  for (int it = 0; it < NIT; ++it) {
    const int buf = it & 1, nbuf = buf ^ 1;
    if (it + 1 < NIT) issueB(it + 1, nbuf);
    if (it + 2 < NIT) aloadTo((it & 1) ? avB : avA, it + 2);  // slot (it+2)&1
#pragma unroll
    for (int kk = 0; kk < 2; ++kk) {
      bf16x8 af[2], bfr[2];
#pragma unroll
      for (int t = 0; t < 2; ++t)
        af[t] = *(const bf16x8*)&As[buf][kk][(t * 16 + c16) * 32 + rx8];
#pragma unroll
      for (int t = 0; t < 2; ++t)
        bfr[t] = *(const bf16x8*)&Bs[buf][kk][(wn + t * 16 + c16) * 32 + rx8];
#pragma unroll
      for (int mt = 0; mt < 2; ++mt)
#pragma unroll
        for (int nt = 0; nt < 2; ++nt)
          acc[mt][nt] = __builtin_amdgcn_mfma_f32_16x16x32_bf16(
              af[mt], bfr[nt], acc[mt][nt], 0, 0, 0);
    }
    if (it + 1 < NIT) awriteFrom((it & 1) ? avA : avB, it + 1, nbuf);  // slot (it+1)&1
    __syncthreads();
  }

#pragma unroll
  for (int nt = 0; nt < 2; ++nt) {
    int col = nBase + wn + nt * 16 + c16;
    float bv = bo[col];
#pragma unroll
    for (int mt = 0; mt < 2; ++mt)
#pragma unroll
      for (int r = 0; r < 4; ++r) {
        int row = mBase + mt * 16 + q4 * 4 + r;
        out[(size_t)row * Nn + col] = acc[mt][nt][r] + bv;
      }
  }
}

// ---------------------------------------------------------------------------
extern "C" void kernel_launch(void* const* d_in, const int* in_sizes, int n_in,
                              void* d_out, int out_size, void* d_ws, size_t ws_size,
                              hipStream_t stream) {
  const float* q    = (const float*)d_in[0];
  const float* k    = (const float*)d_in[1];
  const float* v    = (const float*)d_in[2];
  const int*   mask = (const int*)d_in[3];
  const float* Wq = (const float*)d_in[4];
  const float* bq = (const float*)d_in[5];
  const float* Wk = (const float*)d_in[6];
  const float* bk = (const float*)d_in[7];
  const float* Wv = (const float*)d_in[8];
  const float* bv = (const float*)d_in[9];
  const float* Wo = (const float*)d_in[10];
  const float* bo = (const float*)d_in[11];

  const size_t M2 = (size_t)S_LEN * HID;          // 2M elems
  const size_t W1 = (size_t)HID * HID;            // 1M elems
  // Wbf 4M | (X slot 6M, scratch) | Qb 2M | Kb 2M | Vt 2M | mbits | ...
  // partO z0..z2 -> X slot; partO z3 -> dead Wq/Wk; partL -> dead Wv.
  // Wo (Wbf+3*W1) stays live for gemm_out.
  const size_t need = (4 * W1 + 3 * M2 + 3 * M2) * 2 +
                      (size_t)S_LEN * 64 * 4 + 2 * NHEAD * S_LEN * 4;
  if (ws_size < need) return;   // diagnostic: absmax==0.0752 -> ws too small

  u16* Wbf = (u16*)d_ws;                  // 4M elems
  u16* Xscr = Wbf + 4 * W1;               // 6M elems scratch (partO z0..z2)
  u16* Qb = Xscr + 3 * M2;
  u16* Kb = Qb + M2;
  u16* Vt = Kb + M2;
  unsigned* mbits = (unsigned*)(Vt + M2);
  u16* partOA = Xscr;                     // z0..z2
  u16* partO3 = Wbf;                      // z3 (Wq+Wk dead after qkv)
  float* partL = (float*)(Wbf + 2 * W1);  // Wv region dead after qkv

  hipLaunchKernelGGL(cvt_pack_kernel, dim3(1024, 5), dim3(256), 0, stream,
                     Wq, Wk, Wv, Wo, mask, Wbf, mbits);

  hipLaunchKernelGGL(gemm_qkv, dim3(768), dim3(256), 0, stream,
                     q, k, v, Wbf, bq, bk, bv, Qb, Kb, Vt);

  hipLaunchKernelGGL(attn_kernel, dim3(S_LEN / 256, NHEAD, 4), dim3(512), 0,
                     stream, Qb, Kb, Vt, mbits, partOA, partO3, partL);

  hipLaunchKernelGGL(gemm_out, dim3(512), dim3(256), 0, stream,
                     partOA, partO3, partL, Wbf + 3 * W1, bo, (float*)d_out);
}

// Round 11
// 180.599 us; speedup vs baseline: 1.9148x; 1.9148x over previous
//
#include <hip/hip_runtime.h>
#include <hip/hip_bf16.h>

// MHA forward.  B=1, S=2048, H=1024, NH=16, DK=64.
// Inputs fp32, output fp32.  Internal bf16 MFMA pipeline, fp32 accum.
// Quirk: masked scores -> 0 (not -inf) BEFORE softmax; |scores| <= ~2 so
// softmax needs no max subtraction (m=0) and KV-split partials add.
// R19 (fixes R18's rule-#20 scratch spill):
//  - R18's (it&1)?arB:arA runtime pointer selection put the A-staging
//    slots in SCRATCH (measured: WRITE_SIZE 390MB = 768x256x128Bx16,
//    MfmaUtil 2.7%).  Main loops of gemm_qkv AND gemm_out now unrolled
//    x2 with named even/odd phases -> every slot/buf index is a
//    compile-time constant -> true register residency.  The 2-deep
//    pipeline schedule itself is unchanged.

#define S_LEN 2048
#define HID   1024
#define NHEAD 16
#define DK    64

typedef unsigned short u16;
typedef __attribute__((ext_vector_type(8))) short bf16x8;
typedef __attribute__((ext_vector_type(4))) short bf16x4;
typedef __attribute__((ext_vector_type(4))) float f32x4;
typedef __attribute__((ext_vector_type(2))) unsigned u32x2;
typedef __attribute__((ext_vector_type(4))) unsigned u32x4;

__device__ __forceinline__ void load16_lds(const void* g, void* l) {
  __builtin_amdgcn_global_load_lds(
      (const __attribute__((address_space(1))) void*)g,
      (__attribute__((address_space(3))) void*)l, 16, 0, 0);
}

__device__ __forceinline__ short bfbits(float x) {
  __hip_bfloat16 h = __float2bfloat16(x);
  return *(short*)&h;
}
__device__ __forceinline__ bf16x8 cvt8(float4 a, float4 b) {
  bf16x8 r;
  r[0] = bfbits(a.x); r[1] = bfbits(a.y); r[2] = bfbits(a.z); r[3] = bfbits(a.w);
  r[4] = bfbits(b.x); r[5] = bfbits(b.y); r[6] = bfbits(b.z); r[7] = bfbits(b.w);
  return r;
}
__device__ __forceinline__ float bf2f(u16 u) {
  unsigned v = (unsigned)u << 16;
  return *(float*)&v;
}

// ---------------------------------------------------------------------------
// 0. cvt Wq,Wk,Wv,Wo fp32 -> bf16 (y<4)  AND  pack mask (y==4, row-major).
// ---------------------------------------------------------------------------
__global__ __launch_bounds__(256) void cvt_pack_kernel(
    const float* __restrict__ wq, const float* __restrict__ wk,
    const float* __restrict__ wv, const float* __restrict__ wo,
    const int* __restrict__ mask, u16* __restrict__ Wbf,
    unsigned int* __restrict__ bits) {
  const int y = blockIdx.y;
  if (y == 4) {                       // pack mask -> row-major bitfield
    if (blockIdx.x >= 512) return;
    int idx = blockIdx.x * 256 + threadIdx.x;   // 0 .. 2048*64-1
    const int4* p = (const int4*)(mask + (size_t)idx * 32);
    unsigned word = 0;
#pragma unroll
    for (int i = 0; i < 8; ++i) {
      int4 mv = p[i];
      word |= (unsigned)(mv.x != 0) << (i * 4 + 0);
      word |= (unsigned)(mv.y != 0) << (i * 4 + 1);
      word |= (unsigned)(mv.z != 0) << (i * 4 + 2);
      word |= (unsigned)(mv.w != 0) << (i * 4 + 3);
    }
    bits[idx] = word;
    return;
  }
  if (blockIdx.x >= 512) return;      // 1M elems / 8 / 256 = 512 blocks
  size_t i = ((size_t)blockIdx.x * 256 + threadIdx.x) * 8;
  const float* src = y == 0 ? wq : (y == 1 ? wk : (y == 2 ? wv : wo));
  u16* dst = Wbf + (size_t)y * (HID * HID);
  float4 a = *(const float4*)(src + i);
  float4 b = *(const float4*)(src + i + 4);
  *(bf16x8*)(dst + i) = cvt8(a, b);
}

// ---------------------------------------------------------------------------
// 2. QKV GEMM fused over N=3072: Y = X_z @ W^T + b, z = colgroup>>10.
//    BM=128, BN=64, BK=64, 256 thr / 4 waves, wave tile 64x32.
//    Grid 768 = 3/CU exactly (LDS 48KB, lb(256,3)).
//    A staged REG->LDS with fused fp32->bf16 cvt, 2 iterations deep,
//    STATIC even/odd phases (no runtime slot selection -> registers).
//    B staged via global_load_lds.  XCD mapping: 4m x 24n per XCD.
//    B-LDS slot permutation for adjacent-col packed b32 stores.
//    z=0: *0.125*log2(e) -> Qb ; z=1 -> Kb ; z=2 -> Vt transposed via
//    LDS (coalesced), kv rows permuted so position p holds
//    kv = ((p&7)>>2)*16 + (p>>3)*4 + (p&3)  (attn in-reg P order).
// ---------------------------------------------------------------------------
__global__ __launch_bounds__(256, 3) void gemm_qkv(
    const float* __restrict__ qx, const float* __restrict__ kx,
    const float* __restrict__ vx, const u16* __restrict__ Wbf,
    const float* __restrict__ bq, const float* __restrict__ bk,
    const float* __restrict__ bv, u16* __restrict__ Qb,
    u16* __restrict__ Kb, u16* __restrict__ Vt) {
  constexpr int Mm = 2048, Kk = 1024, NIT = 16;
  const int tid = threadIdx.x, lane = tid & 63, wave = tid >> 6;
  const int q4 = lane >> 4, c16 = lane & 15;
  const int bx = blockIdx.x;                    // 768 blocks
  const int xcd = bx & 7, s = bx >> 3;          // s in [0,96)
  const int mh = s / 24;                        // 0..3
  const int mBase = ((xcd >> 1) * 4 + mh) * 128;
  const int nG = (xcd & 1) * 24 + (s - mh * 24);  // 0..47
  const int nBase = nG * 64;
  const int z = nBase >> 10;
  const float* Araw = z == 0 ? qx : (z == 1 ? kx : vx);
  const float* bias = z == 0 ? bq : (z == 1 ? bk : bv);
  const float oscale = (z == 0) ? 0.125f * 1.44269504088896f : 1.0f;

  const int wr = wave >> 1, wc = wave & 1;      // wave tile 64x32

  __shared__ __align__(16) u16 As[2][2][128 * 32];
  __shared__ __align__(16) u16 Bs[2][2][64 * 32];

  f32x4 acc[4][2] = {};
  const int srow = lane >> 2;
  const int sx8 = ((lane & 3) ^ ((srow >> 1) & 3)) * 8;
  const int rx8 = (q4 ^ ((c16 >> 1) & 3)) * 8;

  // A reg-staging, 2-deep, STATIC slots (arA = even tiles, arB = odd).
  float4 arA[4][2], arB[4][2];

#define QKV_ALOAD(dst, it)                                                  \
  {                                                                         \
    _Pragma("unroll")                                                       \
    for (int j = 0; j < 4; ++j) {                                           \
      int u = wave * 4 + j, hh = u >> 3, grp = u & 7;                       \
      const float* p = Araw + (size_t)(mBase + grp * 16 + srow) * Kk +      \
                       (it) * 64 + hh * 32 + sx8;                           \
      dst[j][0] = *(const float4*)p;                                        \
      dst[j][1] = *(const float4*)(p + 4);                                  \
    }                                                                       \
  }
#define QKV_AWRITE(src, buf)                                                \
  {                                                                         \
    _Pragma("unroll")                                                       \
    for (int j = 0; j < 4; ++j) {                                           \
      int u = wave * 4 + j, hh = u >> 3, grp = u & 7;                       \
      *(bf16x8*)&As[buf][hh][grp * 512 + lane * 8] =                        \
          cvt8(src[j][0], src[j][1]);                                       \
    }                                                                       \
  }

  auto issueB = [&](int it, int buf) {
#pragma unroll
    for (int j = 0; j < 2; ++j) {      // B: 8 units; slot row -> permuted src
      int u = wave * 2 + j, h = u >> 2, grp = u & 3;
      int brow = grp * 16 + srow;                 // LDS slot row 0..63
      int b32 = brow & 31;
      int bsrc = (brow & 32) | ((b32 & 15) * 2 + (b32 >> 4));
      load16_lds(Wbf + (size_t)(nBase + bsrc) * Kk + it * 64 +
                     h * 32 + sx8,
                 &Bs[buf][h][grp * 512]);
    }
  };

  auto mfmaStep = [&](int buf) {
#pragma unroll
    for (int kk = 0; kk < 2; ++kk) {
      bf16x8 af[4], bfr[2];
#pragma unroll
      for (int t = 0; t < 4; ++t)
        af[t] = *(const bf16x8*)&As[buf][kk][(wr * 64 + t * 16 + c16) * 32 + rx8];
#pragma unroll
      for (int t = 0; t < 2; ++t)
        bfr[t] = *(const bf16x8*)&Bs[buf][kk][(wc * 32 + t * 16 + c16) * 32 + rx8];
#pragma unroll
      for (int mt = 0; mt < 4; ++mt)
#pragma unroll
        for (int nt = 0; nt < 2; ++nt)
          acc[mt][nt] = __builtin_amdgcn_mfma_f32_16x16x32_bf16(
              af[mt], bfr[nt], acc[mt][nt], 0, 0, 0);
    }
  };

  // prologue: tile0 -> LDS buf0; tile1 -> arB (written at end of it=0).
  QKV_ALOAD(arA, 0);
  issueB(0, 0);
  QKV_AWRITE(arA, 0);
  QKV_ALOAD(arB, 1);
  __syncthreads();

  for (int itp = 0; itp < NIT; itp += 2) {
    // ---- even it = itp, buf 0 ----
    issueB(itp + 1, 1);                         // itp+1 <= 15 always
    if (itp + 2 < NIT) QKV_ALOAD(arA, itp + 2);
    mfmaStep(0);
    QKV_AWRITE(arB, 1);                         // tile itp+1 -> buf1
    __syncthreads();
    // ---- odd it = itp+1, buf 1 ----
    if (itp + 2 < NIT) issueB(itp + 2, 0);
    if (itp + 3 < NIT) QKV_ALOAD(arB, itp + 3);
    mfmaStep(1);
    if (itp + 2 < NIT) QKV_AWRITE(arA, 0);      // tile itp+2 -> buf0
    __syncthreads();
  }

  // lane's two output cols are ADJACENT: colE, colE+1 (B slot permutation).
  const int colE = wc * 32 + c16 * 2;            // local col, even
  if (z == 2) {
    // ---- LDS transpose: LT[64 cols][132] (reuses As, 16.9KB) ----
    u16* LT = (u16*)&As[0][0][0];
#pragma unroll
    for (int nt = 0; nt < 2; ++nt) {
      int col = colE + nt;
      float bv2 = bias[((nBase & 1023) + col)];
#pragma unroll
      for (int mt = 0; mt < 4; ++mt) {
        int row0 = wr * 64 + mt * 16 + q4 * 4;   // low 2 bits zero
        int vv0 = row0 & 31;
        int rowp0 = (row0 & ~31) | (((vv0 & 15) >> 2) << 3) |
                    (((vv0 >> 4) & 1) << 2);
        bf16x4 t;
#pragma unroll
        for (int r = 0; r < 4; ++r) t[r] = bfbits(acc[mt][nt][r] + bv2);
        *(bf16x4*)&LT[col * 132 + rowp0] = t;
      }
    }
    __syncthreads();
    // readout: 4 reps x 256 thr; 16B coalesced stores along kv.
#pragma unroll
    for (int rep = 0; rep < 4; ++rep) {
      int u = rep * 256 + tid;
      int col = u >> 4, seg = u & 15;
      bf16x8 vvv = *(const bf16x8*)&LT[col * 132 + seg * 8];
      *(bf16x8*)(Vt + (size_t)((nBase & 1023) + col) * Mm + mBase + seg * 8) = vvv;
    }
  } else {
    u16* C = z == 0 ? Qb : Kb;
    int colg = (nBase & 1023) + colE;
    float2 b2 = *(const float2*)&bias[colg];
#pragma unroll
    for (int mt = 0; mt < 4; ++mt) {
#pragma unroll
      for (int r = 0; r < 4; ++r) {
        int row = mBase + wr * 64 + mt * 16 + q4 * 4 + r;
        float v0 = (acc[mt][0][r] + b2.x) * oscale;
        float v1 = (acc[mt][1][r] + b2.y) * oscale;
        unsigned pk;
        asm("v_cvt_pk_bf16_f32 %0, %1, %2" : "=v"(pk) : "v"(v0), "v"(v1));
        *(unsigned*)&C[(size_t)row * 1024 + colg] = pk;
      }
    }
  }
#undef QKV_ALOAD
#undef QKV_AWRITE
}

// ---------------------------------------------------------------------------
// 3. Attention.  8 waves x 32 q-rows = 256 rows/block, 512 thr, KV-split
//    z=4, NITA=8, XCD remap.  SWAPPED QK^T (mfma(K,Q)): lane holds
//    q=c16, kv=q4*4+r -> P packs in-register into the PV A-frag (no LDS
//    P, no lgkmcnt stall).  LDS = K/V dbuf only (33KB); 16 waves/CU.
// ---------------------------------------------------------------------------
__global__ __launch_bounds__(512, 4) void attn_kernel(
    const u16* __restrict__ Qb, const u16* __restrict__ Kb,
    const u16* __restrict__ Vt, const unsigned* __restrict__ mb,
    u16* __restrict__ partOA, u16* __restrict__ partO3,
    float* __restrict__ partL) {
  constexpr int NITA = 8;                       // 512 kv / 64
  const int lin = blockIdx.x + 8 * (blockIdx.y + 16 * blockIdx.z);
  const int work = ((lin & 7) << 6) | (lin >> 3);
  const int qt = work & 7, h = (work >> 3) & 15, zz = work >> 7;
  const int tid = threadIdx.x, lane = tid & 63, wave = tid >> 6;
  const int q4 = lane >> 4, c16 = lane & 15;

  __shared__ __align__(16) u16 Ks[2][2][64 * 32];
  __shared__ __align__(16) u16 Vs[2][2][64 * 32];

  const int q0 = qt * 256 + wave * 32;

  bf16x8 qf[2][2];
#pragma unroll
  for (int m = 0; m < 2; ++m)
#pragma unroll
    for (int kk = 0; kk < 2; ++kk)
      qf[m][kk] = *(const bf16x8*)(Qb + (size_t)(q0 + m * 16 + c16) * HID +
                                   h * DK + kk * 32 + q4 * 8);

  f32x4 o[2][4] = {};
  float l_lane[2] = {0.0f, 0.0f};

  const int srow = lane >> 2;
  const int sx8 = ((lane & 3) ^ ((srow >> 1) & 3)) * 8;
  const int rx8 = (q4 ^ ((c16 >> 1) & 3)) * 8;
  const int kvbase = zz * (S_LEN / 4);

  auto issueKV = [&](int it, int buf) {
    const int kv0 = kvbase + it * 64;
#pragma unroll
    for (int j = 0; j < 2; ++j) {
      int i = wave * 2 + j;          // 0..15
      if (i < 8) {
        int half = i >> 2, grp = i & 3;
        load16_lds(Kb + (size_t)(kv0 + grp * 16 + srow) * HID + h * DK +
                       half * 32 + sx8,
                   &Ks[buf][half][grp * 512]);
      } else {
        int ii = i - 8;
        int half = ii >> 2, grp = ii & 3;
        load16_lds(Vt + (size_t)(h * DK + grp * 16 + srow) * S_LEN + kv0 +
                       half * 32 + sx8,
                   &Vs[buf][half][grp * 512]);
      }
    }
  };

  issueKV(0, 0);
  __syncthreads();

  for (int it = 0; it < NITA; ++it) {
    const int buf = it & 1, nbuf = buf ^ 1;
    if (it + 1 < NITA) issueKV(it + 1, nbuf);

    // mask words: lane's q-row, 2 consecutive kv-words (this 64-kv stripe).
    u32x2 mw[2];
#pragma unroll
    for (int m = 0; m < 2; ++m)
      mw[m] = *(const u32x2*)(mb + (size_t)(q0 + m * 16 + c16) * 64 +
                              (kvbase >> 5) + it * 2);

#pragma unroll
    for (int kk = 0; kk < 2; ++kk) {        // kv-chunk of 32
      // ---- QK^T (swapped): sv[m][ntb] = S^T[kv-tile nt][q] ----
      f32x4 sv[2][2];
      __builtin_amdgcn_s_setprio(1);
#pragma unroll
      for (int ntb = 0; ntb < 2; ++ntb) {
        const int nt = kk * 2 + ntb;
        const int rsw = (nt * 16 + c16) * 32 + rx8;
        bf16x8 kf0 = *(const bf16x8*)&Ks[buf][0][rsw];
        bf16x8 kf1 = *(const bf16x8*)&Ks[buf][1][rsw];
#pragma unroll
        for (int m = 0; m < 2; ++m) {
          f32x4 a = {};
          a = __builtin_amdgcn_mfma_f32_16x16x32_bf16(kf0, qf[m][0], a, 0, 0, 0);
          a = __builtin_amdgcn_mfma_f32_16x16x32_bf16(kf1, qf[m][1], a, 0, 0, 0);
          sv[m][ntb] = a;
        }
      }
      __builtin_amdgcn_s_setprio(0);

      // ---- softmax + in-register pack into PV A-frags ----
      bf16x8 pa[2];
#pragma unroll
      for (int m = 0; m < 2; ++m) {
        const unsigned word = kk ? mw[m][1] : mw[m][0];
        float p[8];
#pragma unroll
        for (int ntb = 0; ntb < 2; ++ntb)
#pragma unroll
          for (int r = 0; r < 4; ++r) {
            const int bit = ntb * 16 + q4 * 4 + r;
            float s = ((word >> bit) & 1u) ? sv[m][ntb][r] : 0.0f;
            float e;
            asm("v_exp_f32 %0, %1" : "=v"(e) : "v"(s));  // log2e pre-folded
            l_lane[m] += e;
            p[ntb * 4 + r] = e;
          }
        u32x4 pk;
#pragma unroll
        for (int j = 0; j < 4; ++j)
          asm("v_cvt_pk_bf16_f32 %0, %1, %2"
              : "=v"(pk[j]) : "v"(p[2 * j]), "v"(p[2 * j + 1]));
        pa[m] = *(bf16x8*)&pk;
      }

      // ---- PV for this kv-chunk ----
      __builtin_amdgcn_s_setprio(1);
#pragma unroll
      for (int ntv = 0; ntv < 4; ++ntv) {
        const int rsw = (ntv * 16 + c16) * 32 + rx8;
        bf16x8 vb = *(const bf16x8*)&Vs[buf][kk][rsw];
        o[0][ntv] = __builtin_amdgcn_mfma_f32_16x16x32_bf16(pa[0], vb, o[0][ntv], 0, 0, 0);
        o[1][ntv] = __builtin_amdgcn_mfma_f32_16x16x32_bf16(pa[1], vb, o[1][ntv], 0, 0, 0);
      }
      __builtin_amdgcn_s_setprio(0);
    }
    __syncthreads();
  }

  u16* pO = (zz < 3) ? (partOA + (size_t)zz * (S_LEN * HID)) : partO3;
#pragma unroll
  for (int m = 0; m < 2; ++m) {
    float s = l_lane[m];
    s += __shfl_xor(s, 16);
    s += __shfl_xor(s, 32);
    int qrow = q0 + m * 16 + c16;
    if (q4 == 0)
      partL[((size_t)zz * NHEAD + h) * S_LEN + qrow] = s;
#pragma unroll
    for (int r = 0; r < 4; ++r) {
      int row = q0 + m * 16 + q4 * 4 + r;
#pragma unroll
      for (int nt = 0; nt < 4; ++nt)
        ((__hip_bfloat16*)pO)[(size_t)row * HID + h * DK + nt * 16 + c16] =
            __float2bfloat16(o[m][nt][r]);
    }
  }
}

// ---------------------------------------------------------------------------
// 5. Output GEMM with fused combine: out = ((O0+O1+O2+O3)/l) @ Wo^T + bo.
//    BM=32, BN=128, 512 blocks = 2/CU, XCD chunking.  A staging 2 iters
//    deep with STATIC even/odd phases (rule-#20-safe).
// ---------------------------------------------------------------------------
__global__ __launch_bounds__(256) void gemm_out(
    const u16* __restrict__ pOA, const u16* __restrict__ pO3,
    const float* __restrict__ partL, const u16* __restrict__ Wo,
    const float* __restrict__ bo, float* __restrict__ out) {
  constexpr int Nn = 1024, Kk = 1024, NIT = 16;
  constexpr size_t M2 = (size_t)S_LEN * HID;
  const int tid = threadIdx.x, lane = tid & 63, wave = tid >> 6;
  const int q4 = lane >> 4, c16 = lane & 15;
  const int bx = blockIdx.x;
  const int xcd = bx & 7, s = bx >> 3;          // s in [0,64)
  const int mBase = (xcd * 8 + (s & 7)) * 32;
  const int nBase = (s >> 3) * 128;
  const int wn = wave * 32;

  __shared__ __align__(16) u16 As[2][2][32 * 32];
  __shared__ __align__(16) u16 Bs[2][2][128 * 32];
  __shared__ float linv[32][16];

  f32x4 acc[2][2] = {};
  const int srow = lane >> 2;
  const int sx8 = ((lane & 3) ^ ((srow >> 1) & 3)) * 8;
  const int rx8 = (q4 ^ ((c16 >> 1) & 3)) * 8;

  const int arow = tid >> 3, acu = tid & 7;     // A unit: row 0..31, colu 0..7
  const int ahalf = acu >> 2;
  const int aoff = arow * 32 + ((acu & 3) ^ ((arow >> 1) & 3)) * 8;

  auto issueB = [&](int it, int buf) {
#pragma unroll
    for (int j = 0; j < 4; ++j) {       // B: 16 units
      int u = wave * 4 + j, h = u >> 3, grp = u & 7;
      load16_lds(Wo + (size_t)(nBase + grp * 16 + srow) * Kk + it * 64 +
                     h * 32 + sx8,
                 &Bs[buf][h][grp * 512]);
    }
  };

  bf16x8 avA[4], avB[4];
#define OUT_ALOAD(dst, it)                                                  \
  {                                                                         \
    const u16* p = pOA + (size_t)(mBase + arow) * Kk + (it) * 64 + acu * 8; \
    dst[0] = *(const bf16x8*)p;                                             \
    dst[1] = *(const bf16x8*)(p + M2);                                      \
    dst[2] = *(const bf16x8*)(p + 2 * M2);                                  \
    dst[3] = *(const bf16x8*)(pO3 + (size_t)(mBase + arow) * Kk +           \
                              (it) * 64 + acu * 8);                         \
  }
#define OUT_AWRITE(src, it, buf)                                            \
  {                                                                         \
    float inv = linv[arow][it];                                             \
    bf16x8 r;                                                               \
    _Pragma("unroll")                                                       \
    for (int j = 0; j < 8; ++j) {                                           \
      float v = (bf2f((u16)src[0][j]) + bf2f((u16)src[1][j]) +              \
                 bf2f((u16)src[2][j]) + bf2f((u16)src[3][j])) * inv;        \
      r[j] = bfbits(v);                                                     \
    }                                                                       \
    *(bf16x8*)&As[buf][ahalf][aoff] = r;                                    \
  }

  auto mfmaStep = [&](int buf) {
#pragma unroll
    for (int kk = 0; kk < 2; ++kk) {
      bf16x8 af[2], bfr[2];
#pragma unroll
      for (int t = 0; t < 2; ++t)
        af[t] = *(const bf16x8*)&As[buf][kk][(t * 16 + c16) * 32 + rx8];
#pragma unroll
      for (int t = 0; t < 2; ++t)
        bfr[t] = *(const bf16x8*)&Bs[buf][kk][(wn + t * 16 + c16) * 32 + rx8];
#pragma unroll
      for (int mt = 0; mt < 2; ++mt)
#pragma unroll
        for (int nt = 0; nt < 2; ++nt)
          acc[mt][nt] = __builtin_amdgcn_mfma_f32_16x16x32_bf16(
              af[mt], bfr[nt], acc[mt][nt], 0, 0, 0);
    }
  };

  // prologue: 1/l table (32 rows x 16 heads), A slots 0,1, B tile 0.
#pragma unroll
  for (int e = 0; e < 2; ++e) {
    int idx = tid * 2 + e, row = idx >> 4, hh = idx & 15;
    float l = 0.0f;
#pragma unroll
    for (int z = 0; z < 4; ++z)
      l += partL[(size_t)(z * NHEAD + hh) * S_LEN + mBase + row];
    linv[row][hh] = 1.0f / l;
  }
  OUT_ALOAD(avA, 0);
  issueB(0, 0);
  __syncthreads();            // linv visible (B0 also drains)
  OUT_AWRITE(avA, 0, 0);
  OUT_ALOAD(avB, 1);
  __syncthreads();            // As[0] + Bs[0] ready

  for (int itp = 0; itp < NIT; itp += 2) {
    // ---- even it = itp, buf 0 ----
    issueB(itp + 1, 1);                          // itp+1 <= 15 always
    if (itp + 2 < NIT) OUT_ALOAD(avA, itp + 2);
    mfmaStep(0);
    OUT_AWRITE(avB, itp + 1, 1);                 // tile itp+1 -> buf1
    __syncthreads();
    // ---- odd it = itp+1, buf 1 ----
    if (itp + 2 < NIT) issueB(itp + 2, 0);
    if (itp + 3 < NIT) OUT_ALOAD(avB, itp + 3);
    mfmaStep(1);
    if (itp + 2 < NIT) OUT_AWRITE(avA, itp + 2, 0);  // tile itp+2 -> buf0
    __syncthreads();
  }

#pragma unroll
  for (int nt = 0; nt < 2; ++nt) {
    int col = nBase + wn + nt * 16 + c16;
    float bv = bo[col];
#pragma unroll
    for (int mt = 0; mt < 2; ++mt)
#pragma unroll
      for (int r = 0; r < 4; ++r) {
        int row = mBase + mt * 16 + q4 * 4 + r;
        out[(size_t)row * Nn + col] = acc[mt][nt][r] + bv;
      }
  }
#undef OUT_ALOAD
#undef OUT_AWRITE
}

// ---------------------------------------------------------------------------
extern "C" void kernel_launch(void* const* d_in, const int* in_sizes, int n_in,
                              void* d_out, int out_size, void* d_ws, size_t ws_size,
                              hipStream_t stream) {
  const float* q    = (const float*)d_in[0];
  const float* k    = (const float*)d_in[1];
  const float* v    = (const float*)d_in[2];
  const int*   mask = (const int*)d_in[3];
  const float* Wq = (const float*)d_in[4];
  const float* bq = (const float*)d_in[5];
  const float* Wk = (const float*)d_in[6];
  const float* bk = (const float*)d_in[7];
  const float* Wv = (const float*)d_in[8];
  const float* bv = (const float*)d_in[9];
  const float* Wo = (const float*)d_in[10];
  const float* bo = (const float*)d_in[11];

  const size_t M2 = (size_t)S_LEN * HID;          // 2M elems
  const size_t W1 = (size_t)HID * HID;            // 1M elems
  // Wbf 4M | (X slot 6M, scratch) | Qb 2M | Kb 2M | Vt 2M | mbits | ...
  // partO z0..z2 -> X slot; partO z3 -> dead Wq/Wk; partL -> dead Wv.
  // Wo (Wbf+3*W1) stays live for gemm_out.
  const size_t need = (4 * W1 + 3 * M2 + 3 * M2) * 2 +
                      (size_t)S_LEN * 64 * 4 + 2 * NHEAD * S_LEN * 4;
  if (ws_size < need) return;   // diagnostic: absmax==0.0752 -> ws too small

  u16* Wbf = (u16*)d_ws;                  // 4M elems
  u16* Xscr = Wbf + 4 * W1;               // 6M elems scratch (partO z0..z2)
  u16* Qb = Xscr + 3 * M2;
  u16* Kb = Qb + M2;
  u16* Vt = Kb + M2;
  unsigned* mbits = (unsigned*)(Vt + M2);
  u16* partOA = Xscr;                     // z0..z2
  u16* partO3 = Wbf;                      // z3 (Wq+Wk dead after qkv)
  float* partL = (float*)(Wbf + 2 * W1);  // Wv region dead after qkv

  hipLaunchKernelGGL(cvt_pack_kernel, dim3(1024, 5), dim3(256), 0, stream,
                     Wq, Wk, Wv, Wo, mask, Wbf, mbits);

  hipLaunchKernelGGL(gemm_qkv, dim3(768), dim3(256), 0, stream,
                     q, k, v, Wbf, bq, bk, bv, Qb, Kb, Vt);

  hipLaunchKernelGGL(attn_kernel, dim3(S_LEN / 256, NHEAD, 4), dim3(512), 0,
                     stream, Qb, Kb, Vt, mbits, partOA, partO3, partL);

  hipLaunchKernelGGL(gemm_out, dim3(512), dim3(256), 0, stream,
                     partOA, partO3, partL, Wbf + 3 * W1, bo, (float*)d_out);
}